// Round 2
// baseline (363.604 us; speedup 1.0000x reference)
//
#include <hip/hip_runtime.h>

// Problem constants (fixed by setup_inputs)
constexpr int S_DIM = 8;
constexpr int B_DIM = 16;
constexpr int H = 512;
constexpr int W = 512;
constexpr int PLANE = H * W;                       // 262144
constexpr long long NTOT = (long long)S_DIM * B_DIM * H * W;  // 33554432
constexpr int NGROUPS = (int)(NTOT / 4);           // 8388608 float4-groups
constexpr int GROUPS_PER_ROW = W / 4;              // 128
constexpr int GROUPS_PER_PLANE = PLANE / 4;        // 65536

__device__ __forceinline__ float weight_of(float t) {
    // w in {1,2,5,10,30} per BALANCING_WEIGHTS thresholds {2,5,10,30}
    float w = 1.0f;
    if (t >= 2.0f)  w = 2.0f;
    if (t >= 5.0f)  w = 5.0f;
    if (t >= 10.0f) w = 10.0f;
    if (t >= 30.0f) w = 30.0f;
    return w;
}

__device__ __forceinline__ float min3(float a, float b, float c) {
    return fminf(fminf(a, b), c);   // clang fuses to v_min3_f32
}

__global__ __launch_bounds__(256)
void wmae_main(const float* __restrict__ pred,
               const float* __restrict__ targ,
               const int*   __restrict__ mask,
               double*      __restrict__ ws_sum) {
    const float BIG = 1e30f;
    float acc = 0.0f;

    const int stride = gridDim.x * blockDim.x;
    for (int gi = blockIdx.x * blockDim.x + threadIdx.x; gi < NGROUPS; gi += stride) {
        const int pl  = gi >> 16;          // / GROUPS_PER_PLANE
        const int rem = gi & (GROUPS_PER_PLANE - 1);
        const int row = rem >> 7;          // / GROUPS_PER_ROW
        const int grp = rem & (GROUPS_PER_ROW - 1);
        const int j0  = grp << 2;

        // target/mask layout: (B,S,H,W), plane index pl = b*S + s
        const int b = pl >> 3;             // / S_DIM
        const int s = pl & 7;

        const size_t toff = (size_t)pl * PLANE + (size_t)row * W + j0;
        const float4 t4 = *reinterpret_cast<const float4*>(targ + toff);
        const int4   m4 = *reinterpret_cast<const int4*>(mask + toff);

        const float w0 = weight_of(t4.x) * (float)m4.x;
        const float w1 = weight_of(t4.y) * (float)m4.y;
        const float w2 = weight_of(t4.z) * (float)m4.z;
        const float w3 = weight_of(t4.w) * (float)m4.w;

        // predicted layout: (S,B,H,W) -> plane (s*B + b)
        const float* pp = pred + (size_t)(s * B_DIM + b) * PLANE;

        float mn0 = BIG, mn1 = BIG, mn2 = BIG, mn3 = BIG;

        const int r_lo = (row > 0)     ? row - 1 : row;      // skip OOB rows
        const int r_hi = (row < H - 1) ? row + 1 : row;

        for (int r = r_lo; r <= r_hi; ++r) {
            const float* pr = pp + (size_t)r * W + j0;
            const float4 p4 = *reinterpret_cast<const float4*>(pr);
            const float pv0 = (grp > 0)                  ? pr[-1] : BIG;
            const float pv5 = (grp < GROUPS_PER_ROW - 1) ? pr[4]  : BIG;
            const float pv1 = p4.x, pv2 = p4.y, pv3 = p4.z, pv4 = p4.w;

            mn0 = fminf(mn0, min3(fabsf(t4.x - pv0), fabsf(t4.x - pv1), fabsf(t4.x - pv2)));
            mn1 = fminf(mn1, min3(fabsf(t4.y - pv1), fabsf(t4.y - pv2), fabsf(t4.y - pv3)));
            mn2 = fminf(mn2, min3(fabsf(t4.z - pv2), fabsf(t4.z - pv3), fabsf(t4.z - pv4)));
            mn3 = fminf(mn3, min3(fabsf(t4.w - pv3), fabsf(t4.w - pv4), fabsf(t4.w - pv5)));
        }

        acc += w0 * mn0 + w1 * mn1 + w2 * mn2 + w3 * mn3;
    }

    // wave64 reduction
    #pragma unroll
    for (int off = 32; off > 0; off >>= 1)
        acc += __shfl_down(acc, off);

    __shared__ float wsum[4];
    const int wid  = threadIdx.x >> 6;
    const int lane = threadIdx.x & 63;
    if (lane == 0) wsum[wid] = acc;
    __syncthreads();
    if (threadIdx.x == 0) {
        const float bsum = wsum[0] + wsum[1] + wsum[2] + wsum[3];
        atomicAdd(ws_sum, (double)bsum);
    }
}

__global__ void wmae_finalize(const double* __restrict__ ws_sum,
                              float* __restrict__ out) {
    out[0] = (float)(ws_sum[0] / (double)NTOT);
}

extern "C" void kernel_launch(void* const* d_in, const int* in_sizes, int n_in,
                              void* d_out, int out_size, void* d_ws, size_t ws_size,
                              hipStream_t stream) {
    const float* predicted = (const float*)d_in[0];  // (S,B,H,W)
    const float* target    = (const float*)d_in[1];  // (B,S,H,W)
    const int*   mask      = (const int*)d_in[2];    // (B,S,H,W)
    float* out  = (float*)d_out;
    double* wsd = (double*)d_ws;

    hipMemsetAsync(wsd, 0, sizeof(double), stream);  // d_ws is poisoned each replay
    wmae_main<<<2048, 256, 0, stream>>>(predicted, target, mask, wsd);
    wmae_finalize<<<1, 1, 0, stream>>>(wsd, out);
}